// Round 10
// baseline (298.711 us; speedup 1.0000x reference)
//
#include <hip/hip_runtime.h>
#include <hip/hip_bf16.h>

#define NODES 100000
#define EDGES 1600000
#define NGRAPH 512
#define BINROWS 256   // rows per bin
#define NBINS 391     // ceil(NODES / 256)
#define BINCAP 6144   // staging slots per bin (mean 4096, sd ~64 -> 32 sigma margin)
#define CHUNK 2048    // edges per binPlace block
#define NCHUNKS ((EDGES + CHUNK - 1) / CHUNK)
#define EPT 8         // edges per thread in binPlace (CHUNK/256)
#define VSS 72        // LDS row stride in shorts (144 B, 16B-aligned for b128)
#define ZROW NODES    // padded zero feature row for inactive edge slots

using bf16 = __hip_bfloat16;
typedef long long ll;
using frag8 = __attribute__((ext_vector_type(8))) short;  // 8 bf16 (4 VGPRs)
using f32x4 = __attribute__((ext_vector_type(4))) float;

__device__ __forceinline__ float lrelu(float v) { return v > 0.0f ? v : 0.2f * v; }

__device__ __forceinline__ unsigned mapf(float f) {
    unsigned u = __float_as_uint(f);
    return (u & 0x80000000u) ? ~u : (u | 0x80000000u);
}
__device__ __forceinline__ float unmapf(unsigned u) {
    return __uint_as_float((u & 0x80000000u) ? (u ^ 0x80000000u) : ~u);
}

__device__ __forceinline__ int idx_at(const void* raw, int i, int f) {
    return f ? (int)((const ll*)raw)[i] : ((const int*)raw)[i];
}

__device__ __forceinline__ unsigned short tobf(float f) {
    bf16 h = __float2bfloat16(f);
    return *reinterpret_cast<unsigned short*>(&h);
}

__global__ void sentinel_kernel(float* out, float v) {
    int i = blockIdx.x * blockDim.x + threadIdx.x;
    if (i < NGRAPH * 10) out[i] = v;
}

// single-pass staging build: sampled int64 self-detect (1 odd word/thread),
// edges loaded ONCE into registers and reused for hist + record passes,
// parallel bin scan + global reservation into fixed-capacity bin slots.
// record = (src << 8) | (dst & 255). 782 blocks (~3/CU).
// NOTE: the LDS sort (recs/binsA) exists to COALESCE the staging writes --
// removing it causes 16x write amplification (round-4 measurement).
__global__ void binPlace(const int* __restrict__ eiw, int* __restrict__ flag,
                         int* __restrict__ binCursor, unsigned* __restrict__ staging) {
    __shared__ unsigned recs[CHUNK];
    __shared__ unsigned short binsA[CHUNK];
    __shared__ int hist[NBINS], lstart[NBINS + 1], baseg[NBINS], lcur[NBINS];
    __shared__ int sc[256];
    __shared__ int red[4];
    int t = threadIdx.x;
    int e0 = blockIdx.x * CHUNK;
    int eEnd = min(e0 + CHUNK, EDGES);
    // sampled self-detect: 256 odd words. ids<2^17 -> int64 odd words all 0;
    // for int32 these words are random node ids (256 simultaneous zeros ~ never)
    int v = 0;
    {
        int kd = e0 + t;
        if (kd < eEnd) v = eiw[2 * kd + 1];
    }
    for (int o = 32; o; o >>= 1) v |= __shfl_xor(v, o);
    if ((t & 63) == 0) red[t >> 6] = v;
    for (int j = t; j < NBINS; j += 256) { hist[j] = 0; lcur[j] = 0; }
    __syncthreads();
    int f = ((red[0] | red[1] | red[2] | red[3]) == 0) ? 1 : 0;
    if (blockIdx.x == 0 && t == 0) flag[0] = f;  // publish for downstream kernels
    const void* ei = (const void*)eiw;
    // load edges ONCE into registers (static-indexed unrolled arrays)
    int sA[EPT], dA[EPT];
#pragma unroll
    for (int u = 0; u < EPT; ++u) {
        int i = e0 + t + u * 256;
        int s = -1, d = -1;
        if (i < eEnd) {
            s = idx_at(ei, i, f);
            d = idx_at(ei, EDGES + i, f);
        }
        sA[u] = s;
        dA[u] = d;
    }
#pragma unroll
    for (int u = 0; u < EPT; ++u)
        if ((unsigned)sA[u] < NODES && (unsigned)dA[u] < NODES)
            atomicAdd(&hist[dA[u] >> 8], 1);
    __syncthreads();
    // parallel exclusive scan over NBINS bins (2 per thread, Hillis-Steele)
    int b0 = t * 2, b1 = t * 2 + 1;
    int h0 = (b0 < NBINS) ? hist[b0] : 0;
    int h1 = (b1 < NBINS) ? hist[b1] : 0;
    int ts = h0 + h1;
    sc[t] = ts;
    __syncthreads();
    for (int o = 1; o < 256; o <<= 1) {
        int u = (t >= o) ? sc[t - o] : 0;
        __syncthreads();
        sc[t] += u;
        __syncthreads();
    }
    int excl = sc[t] - ts;
    if (b0 < NBINS) lstart[b0] = excl;
    if (b1 < NBINS) lstart[b1] = excl + h0;
    if (t == 255) lstart[NBINS] = sc[255];
    __syncthreads();
    for (int j = t; j < NBINS; j += 256)
        if (hist[j] > 0) baseg[j] = atomicAdd(&binCursor[j], hist[j]);
    __syncthreads();
#pragma unroll
    for (int u = 0; u < EPT; ++u) {
        int s = sA[u], d = dA[u];
        if ((unsigned)s < NODES && (unsigned)d < NODES) {
            int bb = d >> 8;
            int p = lstart[bb] + atomicAdd(&lcur[bb], 1);
            recs[p] = ((unsigned)s << 8) | (unsigned)(d & 255);
            binsA[p] = (unsigned short)bb;
        }
    }
    __syncthreads();
    int nv = lstart[NBINS];
    for (int p = t; p < nv; p += 256) {
        int bb = binsA[p];
        int idx = baseg[bb] + (p - lstart[bb]);
        if (idx < BINCAP) staging[(size_t)bb * BINCAP + idx] = recs[p];
    }
}

// one block per 256-row bin (391 blocks): self-compute global offset, staging
// records read ONCE (cached in LDS), WAVE-SHARDED degree hist (4 copies ->
// 4x less same-address atomic contention) + scan -> row_ptr/dinv1/dinv2,
// scatter src into csr_src via per-wave cursors (each wave owns the record
// subset p%256 in its lane range -- same subset in hist and scatter passes,
// so per-wave cursor partitioning is exact; within-row CSR order changes,
// which is irrelevant for sums).
// FUSED: also prescales this block's 256 rows of x into xs (bf16, * dinv1).
// Block 0 writes the ZROW zero pad (h1s pad @12.8MB is beyond the 9.6MB
// staging alias, so it cannot race the staging reads).
__global__ void csr_finalize(const unsigned* __restrict__ staging,
                             const int* __restrict__ binCursor, int* __restrict__ row_ptr,
                             float* __restrict__ dinv1, float* __restrict__ dinv2,
                             int* __restrict__ csr_src, const float* __restrict__ x,
                             bf16* __restrict__ xs, bf16* __restrict__ h1s) {
    __shared__ unsigned stc[BINCAP];      // 24 KB record cache
    __shared__ int lhist4[4][BINROWS];    // wave-sharded hist / cursors
    __shared__ int sc[256];
    __shared__ float d1sh[BINROWS];
    __shared__ int startSh;
    int b = blockIdx.x, t = threadIdx.x;
    int wv = t >> 6;
    int b0 = t * 2, b1 = t * 2 + 1;
    int c0 = (b0 < NBINS) ? binCursor[b0] : 0;
    int c1 = (b1 < NBINS) ? binCursor[b1] : 0;
    sc[t] = ((b0 < b) ? c0 : 0) + ((b1 < b) ? c1 : 0);  // exclusive prefix mask
    __syncthreads();
    for (int o = 128; o; o >>= 1) {
        if (t < o) sc[t] += sc[t + o];
        __syncthreads();
    }
    if (t == 0) startSh = sc[0];
    __syncthreads();
    int myStart = startSh;
    int cnt = binCursor[b];
    if (b == NBINS - 1 && t == 0) row_ptr[NODES] = myStart + cnt;
    const unsigned* st = staging + (size_t)b * BINCAP;
    int r0 = b << 8;
#pragma unroll
    for (int w = 0; w < 4; ++w) lhist4[w][t] = 0;
    __syncthreads();
    // single global read: fill LDS cache + sharded hist in one pass
    for (int p = t; p < cnt; p += 256) {
        unsigned r = st[p];
        stc[p] = r;
        atomicAdd(&lhist4[wv][r & 255], 1);
    }
    __syncthreads();
    int n0 = lhist4[0][t], n1 = lhist4[1][t], n2 = lhist4[2][t], n3 = lhist4[3][t];
    int dg = n0 + n1 + n2 + n3;
    sc[t] = dg;
    __syncthreads();
    for (int o = 1; o < 256; o <<= 1) {
        int u = (t >= o) ? sc[t - o] : 0;
        __syncthreads();
        sc[t] += u;
        __syncthreads();
    }
    int excl = sc[t] - dg;
    int row = r0 + t;
    float dgf = (float)dg;
    float d1 = 1.0f / sqrtf(dgf + 2.0f);
    d1sh[t] = d1;
    if (row < NODES) {
        row_ptr[row] = myStart + excl;
        dinv1[row] = d1;
        dinv2[row] = 1.0f / sqrtf(dgf + 1.0f);
    }
    __syncthreads();
    // per-wave scatter cursors: wave w starts at excl + counts of waves < w
    lhist4[0][t] = excl;
    lhist4[1][t] = excl + n0;
    lhist4[2][t] = excl + n0 + n1;
    lhist4[3][t] = excl + n0 + n1 + n2;
    __syncthreads();
    for (int p = t; p < cnt; p += 256) {
        unsigned rec = stc[p];
        int slot = atomicAdd(&lhist4[wv][rec & 255], 1);
        csr_src[myStart + slot] = (int)(rec >> 8);
    }
    // fused prescale: xs[row] = bf16(x[row] * dinv1[row]) for this block's rows
    for (int i = t; i < BINROWS * 16; i += 256) {
        int lrow = i >> 4;
        int grow = r0 + lrow;
        if (grow >= NODES) break;  // rows are ascending in i
        float4 xv = ((const float4*)x)[(size_t)grow * 16 + (i & 15)];
        float dv = d1sh[lrow];
        uint2 p;
        p.x = (unsigned)tobf(xv.x * dv) | ((unsigned)tobf(xv.y * dv) << 16);
        p.y = (unsigned)tobf(xv.z * dv) | ((unsigned)tobf(xv.w * dv) << 16);
        ((uint2*)xs)[(size_t)grow * 16 + (i & 15)] = p;
    }
    if (b == 0 && t < 16) {  // ZROW zero pad for both feature tables
        uint2 z = make_uint2(0u, 0u);
        ((uint2*)xs)[(size_t)ZROW * 16 + t] = z;
        ((uint2*)h1s)[(size_t)ZROW * 16 + t] = z;
    }
}

__device__ __forceinline__ void unpack_acc(uint2 u, float (&a)[4]) {
    a[0] += __uint_as_float(u.x << 16);
    a[1] += __uint_as_float(u.x & 0xffff0000u);
    a[2] += __uint_as_float(u.y << 16);
    a[3] += __uint_as_float(u.y & 0xffff0000u);
}

// cross-q reduction: lane layout is q*16+c, partial sums live in 4 q-groups
__device__ __forceinline__ void qreduce(float (&a)[4]) {
#pragma unroll
    for (int k = 0; k < 4; ++k) {
        a[k] += __shfl_xor(a[k], 16);
        a[k] += __shfl_xor(a[k], 32);
    }
}

// self term + dinv scale + bf16 pack + Vs store for one row (called lane<16)
__device__ __forceinline__ void finrow(const uint2* __restrict__ feat4,
                                       const float* __restrict__ dinv, float selfw,
                                       short* Vs, int rowBase, int rloc, int c,
                                       const float (&a)[4]) {
    int grow = rowBase + rloc;
    float dv = 0.0f;
    uint2 us = make_uint2(0u, 0u);
    if (grow < NODES) {
        dv = dinv[grow];
        us = feat4[(size_t)grow * 16 + c];
    }
    float v0 = dv * (a[0] + selfw * __uint_as_float(us.x << 16));
    float v1 = dv * (a[1] + selfw * __uint_as_float(us.x & 0xffff0000u));
    float v2 = dv * (a[2] + selfw * __uint_as_float(us.y << 16));
    float v3 = dv * (a[3] + selfw * __uint_as_float(us.y & 0xffff0000u));
    uint2 pk;
    pk.x = (unsigned)tobf(v0) | ((unsigned)tobf(v1) << 16);
    pk.y = (unsigned)tobf(v2) | ((unsigned)tobf(v3) << 16);
    *(uint2*)(Vs + (size_t)rloc * VSS + c * 4) = pk;
}

// shared body: stage W^T, gather 16 rows/wave as 4 chains with a BRANCHLESS
// flattened j-loop at DOUBLE depth: 16 shfls -> 16 ZROW-clamped selects ->
// 16 back-to-back uint2 loads (all in flight together) -> one descending-
// vmcnt accumulate phase. Inactive slots read the zero pad row, so no
// per-lane predication and no per-chain branch blocks.
// acc[nt] C/D layout: col=lane&15, row=quad*4+reg (verified).
__device__ __forceinline__ void gcn_core(const uint2* __restrict__ feat4,
                                         const int* __restrict__ csr,
                                         const int* __restrict__ rp,
                                         const float* __restrict__ dinv, float selfw,
                                         const float* __restrict__ W, short* Vs, short* Wt,
                                         int rowBase, int lane, int wave, f32x4 (&acc)[4]) {
    int t = wave * 64 + lane;
    for (int i = t; i < 4096; i += 256) {  // Wt[n][k] = W[k][n], bf16
        int k = i >> 6, n = i & 63;
        Wt[n * VSS + k] = (short)tobf(W[i]);
    }
    __syncthreads();
    int myBase = rowBase + wave * 16;
    int rpv = (lane < 17) ? rp[min(myBase + lane, NODES)] : 0;
    int q = lane >> 4, c = lane & 15;
    for (int ii = 0; ii < 4; ++ii) {
        int iA = ii, iB = ii + 4, iC = ii + 8, iD = ii + 12;
        int cbA = __shfl(rpv, iA), endA = __shfl(rpv, iA + 1);
        int cbB = __shfl(rpv, iB), endB = __shfl(rpv, iB + 1);
        int cbC = __shfl(rpv, iC), endC = __shfl(rpv, iC + 1);
        int cbD = __shfl(rpv, iD), endD = __shfl(rpv, iD + 1);
        float aA[4] = {0, 0, 0, 0}, aB[4] = {0, 0, 0, 0};
        float aC[4] = {0, 0, 0, 0}, aD[4] = {0, 0, 0, 0};
        while (cbA < endA || cbB < endB || cbC < endC || cbD < endD) {
            int cntA = endA - cbA;
            cntA = cntA > 64 ? 64 : (cntA < 0 ? 0 : cntA);
            int cntB = endB - cbB;
            cntB = cntB > 64 ? 64 : (cntB < 0 ? 0 : cntB);
            int cntC = endC - cbC;
            cntC = cntC > 64 ? 64 : (cntC < 0 ? 0 : cntC);
            int cntD = endD - cbD;
            cntD = cntD > 64 ? 64 : (cntD < 0 ? 0 : cntD);
            int idxA = (lane < cntA) ? csr[cbA + lane] : 0;
            int idxB = (lane < cntB) ? csr[cbB + lane] : 0;
            int idxC = (lane < cntC) ? csr[cbC + lane] : 0;
            int idxD = (lane < cntD) ? csr[cbD + lane] : 0;
            int jm = max(max(cntA, cntB), max(cntC, cntD));
            for (int j = 0; j < jm; j += 16) {
                int e0 = j + q, e1 = j + 4 + q, e2 = j + 8 + q, e3 = j + 12 + q;
                // phase 1: all 16 shfls (one lgkm drain)
                int sA0 = __shfl(idxA, e0), sA1 = __shfl(idxA, e1);
                int sA2 = __shfl(idxA, e2), sA3 = __shfl(idxA, e3);
                int sB0 = __shfl(idxB, e0), sB1 = __shfl(idxB, e1);
                int sB2 = __shfl(idxB, e2), sB3 = __shfl(idxB, e3);
                int sC0 = __shfl(idxC, e0), sC1 = __shfl(idxC, e1);
                int sC2 = __shfl(idxC, e2), sC3 = __shfl(idxC, e3);
                int sD0 = __shfl(idxD, e0), sD1 = __shfl(idxD, e1);
                int sD2 = __shfl(idxD, e2), sD3 = __shfl(idxD, e3);
                // phase 2: ZROW clamp (select, no branch)
                sA0 = (e0 < cntA) ? sA0 : ZROW;
                sA1 = (e1 < cntA) ? sA1 : ZROW;
                sA2 = (e2 < cntA) ? sA2 : ZROW;
                sA3 = (e3 < cntA) ? sA3 : ZROW;
                sB0 = (e0 < cntB) ? sB0 : ZROW;
                sB1 = (e1 < cntB) ? sB1 : ZROW;
                sB2 = (e2 < cntB) ? sB2 : ZROW;
                sB3 = (e3 < cntB) ? sB3 : ZROW;
                sC0 = (e0 < cntC) ? sC0 : ZROW;
                sC1 = (e1 < cntC) ? sC1 : ZROW;
                sC2 = (e2 < cntC) ? sC2 : ZROW;
                sC3 = (e3 < cntC) ? sC3 : ZROW;
                sD0 = (e0 < cntD) ? sD0 : ZROW;
                sD1 = (e1 < cntD) ? sD1 : ZROW;
                sD2 = (e2 < cntD) ? sD2 : ZROW;
                sD3 = (e3 < cntD) ? sD3 : ZROW;
                // phase 3: 16 loads issued back-to-back (all in flight)
                uint2 uA0 = feat4[(size_t)sA0 * 16 + c];
                uint2 uA1 = feat4[(size_t)sA1 * 16 + c];
                uint2 uA2 = feat4[(size_t)sA2 * 16 + c];
                uint2 uA3 = feat4[(size_t)sA3 * 16 + c];
                uint2 uB0 = feat4[(size_t)sB0 * 16 + c];
                uint2 uB1 = feat4[(size_t)sB1 * 16 + c];
                uint2 uB2 = feat4[(size_t)sB2 * 16 + c];
                uint2 uB3 = feat4[(size_t)sB3 * 16 + c];
                uint2 uC0 = feat4[(size_t)sC0 * 16 + c];
                uint2 uC1 = feat4[(size_t)sC1 * 16 + c];
                uint2 uC2 = feat4[(size_t)sC2 * 16 + c];
                uint2 uC3 = feat4[(size_t)sC3 * 16 + c];
                uint2 uD0 = feat4[(size_t)sD0 * 16 + c];
                uint2 uD1 = feat4[(size_t)sD1 * 16 + c];
                uint2 uD2 = feat4[(size_t)sD2 * 16 + c];
                uint2 uD3 = feat4[(size_t)sD3 * 16 + c];
                // phase 4: accumulate (compiler waits vmcnt descending)
                unpack_acc(uA0, aA);
                unpack_acc(uA1, aA);
                unpack_acc(uA2, aA);
                unpack_acc(uA3, aA);
                unpack_acc(uB0, aB);
                unpack_acc(uB1, aB);
                unpack_acc(uB2, aB);
                unpack_acc(uB3, aB);
                unpack_acc(uC0, aC);
                unpack_acc(uC1, aC);
                unpack_acc(uC2, aC);
                unpack_acc(uC3, aC);
                unpack_acc(uD0, aD);
                unpack_acc(uD1, aD);
                unpack_acc(uD2, aD);
                unpack_acc(uD3, aD);
            }
            cbA += 64;
            cbB += 64;
            cbC += 64;
            cbD += 64;
        }
        qreduce(aA);
        qreduce(aB);
        qreduce(aC);
        qreduce(aD);
        if (lane < 16) {
            finrow(feat4, dinv, selfw, Vs, rowBase, wave * 16 + iA, c, aA);
            finrow(feat4, dinv, selfw, Vs, rowBase, wave * 16 + iB, c, aB);
            finrow(feat4, dinv, selfw, Vs, rowBase, wave * 16 + iC, c, aC);
            finrow(feat4, dinv, selfw, Vs, rowBase, wave * 16 + iD, c, aD);
        }
    }
    frag8 afr[2];
    int m = lane & 15;
#pragma unroll
    for (int ks = 0; ks < 2; ++ks)
        afr[ks] = *(frag8*)(Vs + (size_t)(wave * 16 + m) * VSS + q * 8 + ks * 32);
#pragma unroll
    for (int nt = 0; nt < 4; ++nt) {
        f32x4 a = {0.f, 0.f, 0.f, 0.f};
#pragma unroll
        for (int ks = 0; ks < 2; ++ks) {
            frag8 bfr = *(frag8*)(Wt + (size_t)(nt * 16 + m) * VSS + q * 8 + ks * 32);
            a = __builtin_amdgcn_mfma_f32_16x16x32_bf16(afr[ks], bfr, a, 0, 0, 0);
        }
        acc[nt] = a;
    }
}

// layer1: gather + MFMA + bias + LN + leaky -> h1s = h1*dinv2 (bf16)
__global__ void __launch_bounds__(256, 2)
gcn1_fused(const uint2* __restrict__ xs4, const int* __restrict__ csr,
           const int* __restrict__ rp, const float* __restrict__ dinv1,
           const float* __restrict__ dinv2, const float* __restrict__ W1,
           const float* __restrict__ b1, const float* __restrict__ lng,
           const float* __restrict__ lnb, bf16* __restrict__ h1s) {
    __shared__ short sm[2 * 64 * VSS];
    short* Vs = sm;
    short* Wt = sm + 64 * VSS;
    int lane = threadIdx.x & 63, wave = threadIdx.x >> 6;
    int rowBase = blockIdx.x * 64;
    f32x4 acc[4];
    gcn_core(xs4, csr, rp, dinv1, 2.0f, W1, Vs, Wt, rowBase, lane, wave, acc);
    int c = lane & 15, q = lane >> 4;
    float bc[4], lg[4], lb[4];
#pragma unroll
    for (int nt = 0; nt < 4; ++nt) {
        bc[nt] = b1[nt * 16 + c];
        lg[nt] = lng[nt * 16 + c];
        lb[nt] = lnb[nt * 16 + c];
    }
#pragma unroll
    for (int r = 0; r < 4; ++r) {
        int grow = rowBase + wave * 16 + q * 4 + r;
        float v0 = acc[0][r] + bc[0], v1 = acc[1][r] + bc[1];
        float v2 = acc[2][r] + bc[2], v3 = acc[3][r] + bc[3];
        float s = v0 + v1 + v2 + v3;
        for (int o = 1; o < 16; o <<= 1) s += __shfl_xor(s, o);
        float mu = s * (1.0f / 64.0f);
        float d0 = v0 - mu, d1 = v1 - mu, d2 = v2 - mu, d3 = v3 - mu;
        float qq = d0 * d0 + d1 * d1 + d2 * d2 + d3 * d3;
        for (int o = 1; o < 16; o <<= 1) qq += __shfl_xor(qq, o);
        float rstd = 1.0f / sqrtf(qq * (1.0f / 64.0f) + 1e-5f);
        if (grow < NODES) {
            float d2v = dinv2[grow];
            bf16* dst = h1s + (size_t)grow * 64 + c;
            dst[0]  = __float2bfloat16(lrelu(d0 * rstd * lg[0] + lb[0]) * d2v);
            dst[16] = __float2bfloat16(lrelu(d1 * rstd * lg[1] + lb[1]) * d2v);
            dst[32] = __float2bfloat16(lrelu(d2 * rstd * lg[2] + lb[2]) * d2v);
            dst[48] = __float2bfloat16(lrelu(d3 * rstd * lg[3] + lb[3]) * d2v);
        }
    }
}

// layer2: gather + MFMA + bias + leaky + run-merged max-pool
__global__ void __launch_bounds__(256, 2)
gcn2_fused(const uint2* __restrict__ h1s4, const int* __restrict__ csr,
           const int* __restrict__ rp, const float* __restrict__ dinv2,
           const float* __restrict__ W2, const float* __restrict__ b2,
           const void* __restrict__ batch, const int* __restrict__ flag,
           unsigned* __restrict__ pooled) {
    __shared__ short sm[2 * 64 * VSS];
    __shared__ int gsh[64];
    short* Vs = sm;
    short* Wt = sm + 64 * VSS;
    int t = threadIdx.x, lane = t & 63, wave = t >> 6;
    int rowBase = blockIdx.x * 64;
    if (t < 64) {
        int row = rowBase + t;
        gsh[t] = (row < NODES) ? idx_at(batch, row, flag[0]) : -1;
    }
    f32x4 acc[4];
    gcn_core(h1s4, csr, rp, dinv2, 1.0f, W2, Vs, Wt, rowBase, lane, wave, acc);
    int c = lane & 15, q = lane >> 4;
    float bc[4];
#pragma unroll
    for (int nt = 0; nt < 4; ++nt) bc[nt] = b2[nt * 16 + c];
    __syncthreads();
    float* P = (float*)sm;  // 64 x 65 fp32 pool buffer
#pragma unroll
    for (int r = 0; r < 4; ++r) {
        int mloc = wave * 16 + q * 4 + r;
#pragma unroll
        for (int nt = 0; nt < 4; ++nt)
            P[(size_t)mloc * 65 + nt * 16 + c] = lrelu(acc[nt][r] + bc[nt]);
    }
    __syncthreads();
    if (wave == 0) {
        float m = P[lane];
        int gc = gsh[0];
        for (int r = 1; r < 64; ++r) {
            int gr = gsh[r];
            float ar = P[(size_t)r * 65 + lane];
            if (gr == gc) {
                m = fmaxf(m, ar);
            } else {
                if ((unsigned)gc < NGRAPH) atomicMax(&pooled[gc * 64 + lane], mapf(m));
                gc = gr;
                m = ar;
            }
        }
        if ((unsigned)gc < NGRAPH) atomicMax(&pooled[gc * 64 + lane], mapf(m));
    }
}

// head: z = pooled@W3+b3; LN; leaky; z@W4+b4; softmax. One block per graph.
__global__ void head_kernel(const unsigned* __restrict__ pooled, const float* __restrict__ W3,
                            const float* __restrict__ b3, const float* __restrict__ g2,
                            const float* __restrict__ be2, const float* __restrict__ W4,
                            const float* __restrict__ b4, float* __restrict__ out) {
    __shared__ float prow[64];
    __shared__ float z[768];
    __shared__ float rs[4], rss[4];
    __shared__ float mu_s, rstd_s;
    __shared__ float red[10];
    int t = threadIdx.x, gI = blockIdx.x;
    if (t < 64) prow[t] = unmapf(pooled[gI * 64 + t]);
    __syncthreads();
    for (int c = t; c < 768; c += 256) {
        float acc = b3[c];
#pragma unroll 16
        for (int k = 0; k < 64; ++k) acc += prow[k] * W3[k * 768 + c];
        z[c] = acc;
    }
    __syncthreads();
    float s = 0.0f, ss = 0.0f;
    for (int c = t; c < 768; c += 256) {
        float v = z[c];
        s += v;
        ss += v * v;
    }
    for (int o = 32; o; o >>= 1) {
        s += __shfl_xor(s, o);
        ss += __shfl_xor(ss, o);
    }
    if ((t & 63) == 0) { rs[t >> 6] = s; rss[t >> 6] = ss; }
    __syncthreads();
    if (t == 0) {
        float S = rs[0] + rs[1] + rs[2] + rs[3];
        float SS = rss[0] + rss[1] + rss[2] + rss[3];
        float mu = S * (1.0f / 768.0f);
        float var = SS * (1.0f / 768.0f) - mu * mu;
        mu_s = mu;
        rstd_s = 1.0f / sqrtf(fmaxf(var, 0.0f) + 1e-5f);
    }
    __syncthreads();
    for (int c = t; c < 768; c += 256) {
        float y = (z[c] - mu_s) * rstd_s * g2[c] + be2[c];
        z[c] = lrelu(y);
    }
    if (t < 10) red[t] = 0.0f;
    __syncthreads();
    float p[10];
#pragma unroll
    for (int c = 0; c < 10; ++c) p[c] = 0.0f;
    for (int k = t; k < 768; k += 256) {
        float zv = z[k];
#pragma unroll
        for (int c = 0; c < 10; ++c) p[c] += zv * W4[k * 10 + c];
    }
#pragma unroll
    for (int c = 0; c < 10; ++c) atomicAdd(&red[c], p[c]);
    __syncthreads();
    if (t == 0) {
        float l[10], m = -1e30f;
#pragma unroll
        for (int c = 0; c < 10; ++c) {
            l[c] = red[c] + b4[c];
            m = fmaxf(m, l[c]);
        }
        float sum = 0.0f;
#pragma unroll
        for (int c = 0; c < 10; ++c) {
            l[c] = expf(l[c] - m);
            sum += l[c];
        }
        float inv = 1.0f / sum;
#pragma unroll
        for (int c = 0; c < 10; ++c) out[gI * 10 + c] = l[c] * inv;
    }
}

extern "C" void kernel_launch(void* const* d_in, const int* in_sizes, int n_in,
                              void* d_out, int out_size, void* d_ws, size_t ws_size,
                              hipStream_t stream) {
    const size_t REQUIRED = (size_t)(NODES + 1) * 64 * 2 * 2  // xs + h1s (with ZROW pad)
                          + (size_t)EDGES * 4                 // csr_src
                          + (size_t)(NODES + 1) * 4           // row_ptr
                          + (size_t)NODES * 4 * 2             // dinv1, dinv2
                          + (size_t)NBINS * 4                 // binCursor
                          + (size_t)NGRAPH * 64 * 4           // pooled
                          + 16;                               // flag
    if (ws_size < REQUIRED) {
        sentinel_kernel<<<20, 256, 0, stream>>>((float*)d_out, 64.0f);
        return;
    }

    const float* x = (const float*)d_in[0];
    const int* eiw = (const int*)d_in[1];
    const void* batch = d_in[2];
    const float* W1 = (const float*)d_in[3];
    const float* b1 = (const float*)d_in[4];
    const float* lng = (const float*)d_in[5];
    const float* lnb = (const float*)d_in[6];
    const float* W2 = (const float*)d_in[7];
    const float* b2 = (const float*)d_in[8];
    const float* W3 = (const float*)d_in[9];
    const float* b3 = (const float*)d_in[10];
    const float* g2 = (const float*)d_in[11];
    const float* be2 = (const float*)d_in[12];
    const float* W4 = (const float*)d_in[13];
    const float* b4 = (const float*)d_in[14];

    bf16* xs = (bf16*)d_ws;                               // (N+1)*64 bf16
    bf16* h1s = xs + (size_t)(NODES + 1) * 64;            // (N+1)*64 bf16 (12.8 MB)
    unsigned* staging = (unsigned*)h1s;                   // NBINS*BINCAP*4 = 9.61 MB alias
    int* csr_src = (int*)(h1s + (size_t)(NODES + 1) * 64);  // E
    int* row_ptr = csr_src + EDGES;                       // N+1
    float* dinv1 = (float*)(row_ptr + NODES + 1);         // N
    float* dinv2 = dinv1 + NODES;                         // N
    int* binCursor = (int*)(dinv2 + NODES);               // NBINS
    unsigned* pooled = (unsigned*)(binCursor + NBINS);    // G*64 (adjacent to binCursor)
    int* flag = (int*)(pooled + NGRAPH * 64);             // 1

    // one merged memset: binCursor=0 and pooled sentinel=0 (adjacent regions;
    // 0x00000000 < mapf(v) for every real float v)
    hipMemsetAsync(binCursor, 0, ((size_t)NBINS + (size_t)NGRAPH * 64) * 4, stream);

    // staging build (single edge-pass kernel; fixed-capacity bin slots)
    binPlace<<<NCHUNKS, 256, 0, stream>>>(eiw, flag, binCursor, staging);
    // csr_finalize also prescales x into xs (fused)
    csr_finalize<<<NBINS, 256, 0, stream>>>(staging, binCursor, row_ptr, dinv1, dinv2,
                                            csr_src, x, xs, h1s);

    // fused layers: 64 rows/block, 4-chain branchless-window gather (16 loads
    // in flight) + MFMA
    gcn1_fused<<<(NODES + 63) / 64, 256, 0, stream>>>((const uint2*)xs, csr_src, row_ptr,
                                                      dinv1, dinv2, W1, b1, lng, lnb, h1s);
    gcn2_fused<<<(NODES + 63) / 64, 256, 0, stream>>>((const uint2*)h1s, csr_src, row_ptr,
                                                      dinv2, W2, b2, batch, flag, pooled);

    // head
    head_kernel<<<NGRAPH, 256, 0, stream>>>(pooled, W3, b3, g2, be2, W4, b4, (float*)d_out);
}

// Round 11
// 277.732 us; speedup vs baseline: 1.0755x; 1.0755x over previous
//
#include <hip/hip_runtime.h>
#include <hip/hip_bf16.h>

#define NODES 100000
#define EDGES 1600000
#define NGRAPH 512
#define BINROWS 256   // rows per bin
#define NBINS 391     // ceil(NODES / 256)
#define BINCAP 6144   // staging slots per bin (mean 4096, sd ~64 -> 32 sigma margin)
#define CHUNK 2048    // edges per binPlace block
#define NCHUNKS ((EDGES + CHUNK - 1) / CHUNK)
#define EPT 8         // edges per thread in binPlace (CHUNK/256)
#define VSS 72        // LDS row stride in shorts (144 B, 16B-aligned for b128)
#define ZROW NODES    // padded zero feature row for inactive edge slots

using bf16 = __hip_bfloat16;
typedef long long ll;
using frag8 = __attribute__((ext_vector_type(8))) short;  // 8 bf16 (4 VGPRs)
using f32x4 = __attribute__((ext_vector_type(4))) float;

__device__ __forceinline__ float lrelu(float v) { return v > 0.0f ? v : 0.2f * v; }

__device__ __forceinline__ unsigned mapf(float f) {
    unsigned u = __float_as_uint(f);
    return (u & 0x80000000u) ? ~u : (u | 0x80000000u);
}
__device__ __forceinline__ float unmapf(unsigned u) {
    return __uint_as_float((u & 0x80000000u) ? (u ^ 0x80000000u) : ~u);
}

__device__ __forceinline__ int idx_at(const void* raw, int i, int f) {
    return f ? (int)((const ll*)raw)[i] : ((const int*)raw)[i];
}

__device__ __forceinline__ unsigned short tobf(float f) {
    bf16 h = __float2bfloat16(f);
    return *reinterpret_cast<unsigned short*>(&h);
}

__global__ void sentinel_kernel(float* out, float v) {
    int i = blockIdx.x * blockDim.x + threadIdx.x;
    if (i < NGRAPH * 10) out[i] = v;
}

// single-pass staging build: sampled int64 self-detect (1 odd word/thread),
// edges loaded ONCE into registers and reused for hist + record passes,
// parallel bin scan + global reservation into fixed-capacity bin slots.
// record = (src << 8) | (dst & 255). 782 blocks (~3/CU).
// NOTE: the LDS sort (recs/binsA) exists to COALESCE the staging writes --
// removing it causes 16x write amplification (round-4 measurement).
__global__ void binPlace(const int* __restrict__ eiw, int* __restrict__ flag,
                         int* __restrict__ binCursor, unsigned* __restrict__ staging) {
    __shared__ unsigned recs[CHUNK];
    __shared__ unsigned short binsA[CHUNK];
    __shared__ int hist[NBINS], lstart[NBINS + 1], baseg[NBINS], lcur[NBINS];
    __shared__ int sc[256];
    __shared__ int red[4];
    int t = threadIdx.x;
    int e0 = blockIdx.x * CHUNK;
    int eEnd = min(e0 + CHUNK, EDGES);
    // sampled self-detect: 256 odd words. ids<2^17 -> int64 odd words all 0;
    // for int32 these words are random node ids (256 simultaneous zeros ~ never)
    int v = 0;
    {
        int kd = e0 + t;
        if (kd < eEnd) v = eiw[2 * kd + 1];
    }
    for (int o = 32; o; o >>= 1) v |= __shfl_xor(v, o);
    if ((t & 63) == 0) red[t >> 6] = v;
    for (int j = t; j < NBINS; j += 256) { hist[j] = 0; lcur[j] = 0; }
    __syncthreads();
    int f = ((red[0] | red[1] | red[2] | red[3]) == 0) ? 1 : 0;
    if (blockIdx.x == 0 && t == 0) flag[0] = f;  // publish for downstream kernels
    const void* ei = (const void*)eiw;
    // load edges ONCE into registers (static-indexed unrolled arrays)
    int sA[EPT], dA[EPT];
#pragma unroll
    for (int u = 0; u < EPT; ++u) {
        int i = e0 + t + u * 256;
        int s = -1, d = -1;
        if (i < eEnd) {
            s = idx_at(ei, i, f);
            d = idx_at(ei, EDGES + i, f);
        }
        sA[u] = s;
        dA[u] = d;
    }
#pragma unroll
    for (int u = 0; u < EPT; ++u)
        if ((unsigned)sA[u] < NODES && (unsigned)dA[u] < NODES)
            atomicAdd(&hist[dA[u] >> 8], 1);
    __syncthreads();
    // parallel exclusive scan over NBINS bins (2 per thread, Hillis-Steele)
    int b0 = t * 2, b1 = t * 2 + 1;
    int h0 = (b0 < NBINS) ? hist[b0] : 0;
    int h1 = (b1 < NBINS) ? hist[b1] : 0;
    int ts = h0 + h1;
    sc[t] = ts;
    __syncthreads();
    for (int o = 1; o < 256; o <<= 1) {
        int u = (t >= o) ? sc[t - o] : 0;
        __syncthreads();
        sc[t] += u;
        __syncthreads();
    }
    int excl = sc[t] - ts;
    if (b0 < NBINS) lstart[b0] = excl;
    if (b1 < NBINS) lstart[b1] = excl + h0;
    if (t == 255) lstart[NBINS] = sc[255];
    __syncthreads();
    for (int j = t; j < NBINS; j += 256)
        if (hist[j] > 0) baseg[j] = atomicAdd(&binCursor[j], hist[j]);
    __syncthreads();
#pragma unroll
    for (int u = 0; u < EPT; ++u) {
        int s = sA[u], d = dA[u];
        if ((unsigned)s < NODES && (unsigned)d < NODES) {
            int bb = d >> 8;
            int p = lstart[bb] + atomicAdd(&lcur[bb], 1);
            recs[p] = ((unsigned)s << 8) | (unsigned)(d & 255);
            binsA[p] = (unsigned short)bb;
        }
    }
    __syncthreads();
    int nv = lstart[NBINS];
    for (int p = t; p < nv; p += 256) {
        int bb = binsA[p];
        int idx = baseg[bb] + (p - lstart[bb]);
        if (idx < BINCAP) staging[(size_t)bb * BINCAP + idx] = recs[p];
    }
}

// one block per 256-row bin (391 blocks): self-compute global offset, staging
// records read ONCE (cached in LDS for the scatter pass), local degree hist
// (1 row/thread) + scan -> row_ptr/dinv1/dinv2, scatter src into csr_src.
// FUSED: also prescales this block's 256 rows of x into xs (bf16, * dinv1).
// Block 0 writes the ZROW zero pad (h1s pad @12.8MB is beyond the 9.6MB
// staging alias, so it cannot race the staging reads).
__global__ void csr_finalize(const unsigned* __restrict__ staging,
                             const int* __restrict__ binCursor, int* __restrict__ row_ptr,
                             float* __restrict__ dinv1, float* __restrict__ dinv2,
                             int* __restrict__ csr_src, const float* __restrict__ x,
                             bf16* __restrict__ xs, bf16* __restrict__ h1s) {
    __shared__ unsigned stc[BINCAP];  // 24 KB record cache
    __shared__ int lhist[BINROWS];
    __shared__ int sc[256];
    __shared__ float d1sh[BINROWS];
    __shared__ int startSh;
    int b = blockIdx.x, t = threadIdx.x;
    int b0 = t * 2, b1 = t * 2 + 1;
    int c0 = (b0 < NBINS) ? binCursor[b0] : 0;
    int c1 = (b1 < NBINS) ? binCursor[b1] : 0;
    sc[t] = ((b0 < b) ? c0 : 0) + ((b1 < b) ? c1 : 0);  // exclusive prefix mask
    __syncthreads();
    for (int o = 128; o; o >>= 1) {
        if (t < o) sc[t] += sc[t + o];
        __syncthreads();
    }
    if (t == 0) startSh = sc[0];
    __syncthreads();
    int myStart = startSh;
    int cnt = binCursor[b];
    if (b == NBINS - 1 && t == 0) row_ptr[NODES] = myStart + cnt;
    const unsigned* st = staging + (size_t)b * BINCAP;
    int r0 = b << 8;
    lhist[t] = 0;
    __syncthreads();
    // single global read: fill LDS cache + hist in one pass
    for (int p = t; p < cnt; p += 256) {
        unsigned r = st[p];
        stc[p] = r;
        atomicAdd(&lhist[r & 255], 1);
    }
    __syncthreads();
    int dg = lhist[t];
    sc[t] = dg;
    __syncthreads();
    for (int o = 1; o < 256; o <<= 1) {
        int u = (t >= o) ? sc[t - o] : 0;
        __syncthreads();
        sc[t] += u;
        __syncthreads();
    }
    int excl = sc[t] - dg;
    int row = r0 + t;
    float dgf = (float)dg;
    float d1 = 1.0f / sqrtf(dgf + 2.0f);
    d1sh[t] = d1;
    if (row < NODES) {
        row_ptr[row] = myStart + excl;
        dinv1[row] = d1;
        dinv2[row] = 1.0f / sqrtf(dgf + 1.0f);
    }
    __syncthreads();
    lhist[t] = excl;
    __syncthreads();
    for (int p = t; p < cnt; p += 256) {
        unsigned rec = stc[p];
        int slot = atomicAdd(&lhist[rec & 255], 1);
        csr_src[myStart + slot] = (int)(rec >> 8);
    }
    // fused prescale: xs[row] = bf16(x[row] * dinv1[row]) for this block's rows
    for (int i = t; i < BINROWS * 16; i += 256) {
        int lrow = i >> 4;
        int grow = r0 + lrow;
        if (grow >= NODES) break;  // rows are ascending in i
        float4 xv = ((const float4*)x)[(size_t)grow * 16 + (i & 15)];
        float dv = d1sh[lrow];
        uint2 p;
        p.x = (unsigned)tobf(xv.x * dv) | ((unsigned)tobf(xv.y * dv) << 16);
        p.y = (unsigned)tobf(xv.z * dv) | ((unsigned)tobf(xv.w * dv) << 16);
        ((uint2*)xs)[(size_t)grow * 16 + (i & 15)] = p;
    }
    if (b == 0 && t < 16) {  // ZROW zero pad for both feature tables
        uint2 z = make_uint2(0u, 0u);
        ((uint2*)xs)[(size_t)ZROW * 16 + t] = z;
        ((uint2*)h1s)[(size_t)ZROW * 16 + t] = z;
    }
}

__device__ __forceinline__ void unpack_acc(uint2 u, float (&a)[4]) {
    a[0] += __uint_as_float(u.x << 16);
    a[1] += __uint_as_float(u.x & 0xffff0000u);
    a[2] += __uint_as_float(u.y << 16);
    a[3] += __uint_as_float(u.y & 0xffff0000u);
}

// cross-q reduction: lane layout is q*16+c, partial sums live in 4 q-groups
__device__ __forceinline__ void qreduce(float (&a)[4]) {
#pragma unroll
    for (int k = 0; k < 4; ++k) {
        a[k] += __shfl_xor(a[k], 16);
        a[k] += __shfl_xor(a[k], 32);
    }
}

// self term + dinv scale + bf16 pack + Vs store for one row (called lane<16)
__device__ __forceinline__ void finrow(const uint2* __restrict__ feat4,
                                       const float* __restrict__ dinv, float selfw,
                                       short* Vs, int rowBase, int rloc, int c,
                                       const float (&a)[4]) {
    int grow = rowBase + rloc;
    float dv = 0.0f;
    uint2 us = make_uint2(0u, 0u);
    if (grow < NODES) {
        dv = dinv[grow];
        us = feat4[(size_t)grow * 16 + c];
    }
    float v0 = dv * (a[0] + selfw * __uint_as_float(us.x << 16));
    float v1 = dv * (a[1] + selfw * __uint_as_float(us.x & 0xffff0000u));
    float v2 = dv * (a[2] + selfw * __uint_as_float(us.y << 16));
    float v3 = dv * (a[3] + selfw * __uint_as_float(us.y & 0xffff0000u));
    uint2 pk;
    pk.x = (unsigned)tobf(v0) | ((unsigned)tobf(v1) << 16);
    pk.y = (unsigned)tobf(v2) | ((unsigned)tobf(v3) << 16);
    *(uint2*)(Vs + (size_t)rloc * VSS + c * 4) = pk;
}

// shared body: stage W^T, gather 16 rows/wave as 4 chains with a BRANCHLESS
// flattened j-loop: 8 shfls -> 8 ZROW-clamped index selects -> 8 back-to-back
// uint2 loads (all in flight together) -> one descending-vmcnt accumulate
// phase. Inactive slots read the zero pad row, so no per-lane predication and
// no per-chain branch blocks. 8 loads in flight is the measured knee:
// 4 (r5) neutral, 16 (r10) regressed (waste + longer wait chains).
// acc[nt] C/D layout: col=lane&15, row=quad*4+reg (verified).
__device__ __forceinline__ void gcn_core(const uint2* __restrict__ feat4,
                                         const int* __restrict__ csr,
                                         const int* __restrict__ rp,
                                         const float* __restrict__ dinv, float selfw,
                                         const float* __restrict__ W, short* Vs, short* Wt,
                                         int rowBase, int lane, int wave, f32x4 (&acc)[4]) {
    int t = wave * 64 + lane;
    for (int i = t; i < 4096; i += 256) {  // Wt[n][k] = W[k][n], bf16
        int k = i >> 6, n = i & 63;
        Wt[n * VSS + k] = (short)tobf(W[i]);
    }
    __syncthreads();
    int myBase = rowBase + wave * 16;
    int rpv = (lane < 17) ? rp[min(myBase + lane, NODES)] : 0;
    int q = lane >> 4, c = lane & 15;
    for (int ii = 0; ii < 4; ++ii) {
        int iA = ii, iB = ii + 4, iC = ii + 8, iD = ii + 12;
        int cbA = __shfl(rpv, iA), endA = __shfl(rpv, iA + 1);
        int cbB = __shfl(rpv, iB), endB = __shfl(rpv, iB + 1);
        int cbC = __shfl(rpv, iC), endC = __shfl(rpv, iC + 1);
        int cbD = __shfl(rpv, iD), endD = __shfl(rpv, iD + 1);
        float aA[4] = {0, 0, 0, 0}, aB[4] = {0, 0, 0, 0};
        float aC[4] = {0, 0, 0, 0}, aD[4] = {0, 0, 0, 0};
        while (cbA < endA || cbB < endB || cbC < endC || cbD < endD) {
            int cntA = endA - cbA;
            cntA = cntA > 64 ? 64 : (cntA < 0 ? 0 : cntA);
            int cntB = endB - cbB;
            cntB = cntB > 64 ? 64 : (cntB < 0 ? 0 : cntB);
            int cntC = endC - cbC;
            cntC = cntC > 64 ? 64 : (cntC < 0 ? 0 : cntC);
            int cntD = endD - cbD;
            cntD = cntD > 64 ? 64 : (cntD < 0 ? 0 : cntD);
            int idxA = (lane < cntA) ? csr[cbA + lane] : 0;
            int idxB = (lane < cntB) ? csr[cbB + lane] : 0;
            int idxC = (lane < cntC) ? csr[cbC + lane] : 0;
            int idxD = (lane < cntD) ? csr[cbD + lane] : 0;
            int jm = max(max(cntA, cntB), max(cntC, cntD));
            for (int j = 0; j < jm; j += 8) {
                int e0 = j + q, e1 = j + 4 + q;
                // phase 1: all shfls (one lgkm drain)
                int sA0 = __shfl(idxA, e0), sA1 = __shfl(idxA, e1);
                int sB0 = __shfl(idxB, e0), sB1 = __shfl(idxB, e1);
                int sC0 = __shfl(idxC, e0), sC1 = __shfl(idxC, e1);
                int sD0 = __shfl(idxD, e0), sD1 = __shfl(idxD, e1);
                // phase 2: ZROW clamp (select, no branch)
                sA0 = (e0 < cntA) ? sA0 : ZROW;
                sA1 = (e1 < cntA) ? sA1 : ZROW;
                sB0 = (e0 < cntB) ? sB0 : ZROW;
                sB1 = (e1 < cntB) ? sB1 : ZROW;
                sC0 = (e0 < cntC) ? sC0 : ZROW;
                sC1 = (e1 < cntC) ? sC1 : ZROW;
                sD0 = (e0 < cntD) ? sD0 : ZROW;
                sD1 = (e1 < cntD) ? sD1 : ZROW;
                // phase 3: 8 loads issued back-to-back (all in flight)
                uint2 uA0 = feat4[(size_t)sA0 * 16 + c];
                uint2 uA1 = feat4[(size_t)sA1 * 16 + c];
                uint2 uB0 = feat4[(size_t)sB0 * 16 + c];
                uint2 uB1 = feat4[(size_t)sB1 * 16 + c];
                uint2 uC0 = feat4[(size_t)sC0 * 16 + c];
                uint2 uC1 = feat4[(size_t)sC1 * 16 + c];
                uint2 uD0 = feat4[(size_t)sD0 * 16 + c];
                uint2 uD1 = feat4[(size_t)sD1 * 16 + c];
                // phase 4: accumulate (compiler waits vmcnt descending)
                unpack_acc(uA0, aA);
                unpack_acc(uA1, aA);
                unpack_acc(uB0, aB);
                unpack_acc(uB1, aB);
                unpack_acc(uC0, aC);
                unpack_acc(uC1, aC);
                unpack_acc(uD0, aD);
                unpack_acc(uD1, aD);
            }
            cbA += 64;
            cbB += 64;
            cbC += 64;
            cbD += 64;
        }
        qreduce(aA);
        qreduce(aB);
        qreduce(aC);
        qreduce(aD);
        if (lane < 16) {
            finrow(feat4, dinv, selfw, Vs, rowBase, wave * 16 + iA, c, aA);
            finrow(feat4, dinv, selfw, Vs, rowBase, wave * 16 + iB, c, aB);
            finrow(feat4, dinv, selfw, Vs, rowBase, wave * 16 + iC, c, aC);
            finrow(feat4, dinv, selfw, Vs, rowBase, wave * 16 + iD, c, aD);
        }
    }
    frag8 afr[2];
    int m = lane & 15;
#pragma unroll
    for (int ks = 0; ks < 2; ++ks)
        afr[ks] = *(frag8*)(Vs + (size_t)(wave * 16 + m) * VSS + q * 8 + ks * 32);
#pragma unroll
    for (int nt = 0; nt < 4; ++nt) {
        f32x4 a = {0.f, 0.f, 0.f, 0.f};
#pragma unroll
        for (int ks = 0; ks < 2; ++ks) {
            frag8 bfr = *(frag8*)(Wt + (size_t)(nt * 16 + m) * VSS + q * 8 + ks * 32);
            a = __builtin_amdgcn_mfma_f32_16x16x32_bf16(afr[ks], bfr, a, 0, 0, 0);
        }
        acc[nt] = a;
    }
}

// layer1: gather + MFMA + bias + LN + leaky -> h1s = h1*dinv2 (bf16)
__global__ void __launch_bounds__(256, 2)
gcn1_fused(const uint2* __restrict__ xs4, const int* __restrict__ csr,
           const int* __restrict__ rp, const float* __restrict__ dinv1,
           const float* __restrict__ dinv2, const float* __restrict__ W1,
           const float* __restrict__ b1, const float* __restrict__ lng,
           const float* __restrict__ lnb, bf16* __restrict__ h1s) {
    __shared__ short sm[2 * 64 * VSS];
    short* Vs = sm;
    short* Wt = sm + 64 * VSS;
    int lane = threadIdx.x & 63, wave = threadIdx.x >> 6;
    int rowBase = blockIdx.x * 64;
    f32x4 acc[4];
    gcn_core(xs4, csr, rp, dinv1, 2.0f, W1, Vs, Wt, rowBase, lane, wave, acc);
    int c = lane & 15, q = lane >> 4;
    float bc[4], lg[4], lb[4];
#pragma unroll
    for (int nt = 0; nt < 4; ++nt) {
        bc[nt] = b1[nt * 16 + c];
        lg[nt] = lng[nt * 16 + c];
        lb[nt] = lnb[nt * 16 + c];
    }
#pragma unroll
    for (int r = 0; r < 4; ++r) {
        int grow = rowBase + wave * 16 + q * 4 + r;
        float v0 = acc[0][r] + bc[0], v1 = acc[1][r] + bc[1];
        float v2 = acc[2][r] + bc[2], v3 = acc[3][r] + bc[3];
        float s = v0 + v1 + v2 + v3;
        for (int o = 1; o < 16; o <<= 1) s += __shfl_xor(s, o);
        float mu = s * (1.0f / 64.0f);
        float d0 = v0 - mu, d1 = v1 - mu, d2 = v2 - mu, d3 = v3 - mu;
        float qq = d0 * d0 + d1 * d1 + d2 * d2 + d3 * d3;
        for (int o = 1; o < 16; o <<= 1) qq += __shfl_xor(qq, o);
        float rstd = 1.0f / sqrtf(qq * (1.0f / 64.0f) + 1e-5f);
        if (grow < NODES) {
            float d2v = dinv2[grow];
            bf16* dst = h1s + (size_t)grow * 64 + c;
            dst[0]  = __float2bfloat16(lrelu(d0 * rstd * lg[0] + lb[0]) * d2v);
            dst[16] = __float2bfloat16(lrelu(d1 * rstd * lg[1] + lb[1]) * d2v);
            dst[32] = __float2bfloat16(lrelu(d2 * rstd * lg[2] + lb[2]) * d2v);
            dst[48] = __float2bfloat16(lrelu(d3 * rstd * lg[3] + lb[3]) * d2v);
        }
    }
}

// layer2: gather + MFMA + bias + leaky + run-merged max-pool
__global__ void __launch_bounds__(256, 2)
gcn2_fused(const uint2* __restrict__ h1s4, const int* __restrict__ csr,
           const int* __restrict__ rp, const float* __restrict__ dinv2,
           const float* __restrict__ W2, const float* __restrict__ b2,
           const void* __restrict__ batch, const int* __restrict__ flag,
           unsigned* __restrict__ pooled) {
    __shared__ short sm[2 * 64 * VSS];
    __shared__ int gsh[64];
    short* Vs = sm;
    short* Wt = sm + 64 * VSS;
    int t = threadIdx.x, lane = t & 63, wave = t >> 6;
    int rowBase = blockIdx.x * 64;
    if (t < 64) {
        int row = rowBase + t;
        gsh[t] = (row < NODES) ? idx_at(batch, row, flag[0]) : -1;
    }
    f32x4 acc[4];
    gcn_core(h1s4, csr, rp, dinv2, 1.0f, W2, Vs, Wt, rowBase, lane, wave, acc);
    int c = lane & 15, q = lane >> 4;
    float bc[4];
#pragma unroll
    for (int nt = 0; nt < 4; ++nt) bc[nt] = b2[nt * 16 + c];
    __syncthreads();
    float* P = (float*)sm;  // 64 x 65 fp32 pool buffer
#pragma unroll
    for (int r = 0; r < 4; ++r) {
        int mloc = wave * 16 + q * 4 + r;
#pragma unroll
        for (int nt = 0; nt < 4; ++nt)
            P[(size_t)mloc * 65 + nt * 16 + c] = lrelu(acc[nt][r] + bc[nt]);
    }
    __syncthreads();
    if (wave == 0) {
        float m = P[lane];
        int gc = gsh[0];
        for (int r = 1; r < 64; ++r) {
            int gr = gsh[r];
            float ar = P[(size_t)r * 65 + lane];
            if (gr == gc) {
                m = fmaxf(m, ar);
            } else {
                if ((unsigned)gc < NGRAPH) atomicMax(&pooled[gc * 64 + lane], mapf(m));
                gc = gr;
                m = ar;
            }
        }
        if ((unsigned)gc < NGRAPH) atomicMax(&pooled[gc * 64 + lane], mapf(m));
    }
}

// head: z = pooled@W3+b3; LN; leaky; z@W4+b4; softmax. One block per graph.
__global__ void head_kernel(const unsigned* __restrict__ pooled, const float* __restrict__ W3,
                            const float* __restrict__ b3, const float* __restrict__ g2,
                            const float* __restrict__ be2, const float* __restrict__ W4,
                            const float* __restrict__ b4, float* __restrict__ out) {
    __shared__ float prow[64];
    __shared__ float z[768];
    __shared__ float rs[4], rss[4];
    __shared__ float mu_s, rstd_s;
    __shared__ float red[10];
    int t = threadIdx.x, gI = blockIdx.x;
    if (t < 64) prow[t] = unmapf(pooled[gI * 64 + t]);
    __syncthreads();
    for (int c = t; c < 768; c += 256) {
        float acc = b3[c];
#pragma unroll 16
        for (int k = 0; k < 64; ++k) acc += prow[k] * W3[k * 768 + c];
        z[c] = acc;
    }
    __syncthreads();
    float s = 0.0f, ss = 0.0f;
    for (int c = t; c < 768; c += 256) {
        float v = z[c];
        s += v;
        ss += v * v;
    }
    for (int o = 32; o; o >>= 1) {
        s += __shfl_xor(s, o);
        ss += __shfl_xor(ss, o);
    }
    if ((t & 63) == 0) { rs[t >> 6] = s; rss[t >> 6] = ss; }
    __syncthreads();
    if (t == 0) {
        float S = rs[0] + rs[1] + rs[2] + rs[3];
        float SS = rss[0] + rss[1] + rss[2] + rss[3];
        float mu = S * (1.0f / 768.0f);
        float var = SS * (1.0f / 768.0f) - mu * mu;
        mu_s = mu;
        rstd_s = 1.0f / sqrtf(fmaxf(var, 0.0f) + 1e-5f);
    }
    __syncthreads();
    for (int c = t; c < 768; c += 256) {
        float y = (z[c] - mu_s) * rstd_s * g2[c] + be2[c];
        z[c] = lrelu(y);
    }
    if (t < 10) red[t] = 0.0f;
    __syncthreads();
    float p[10];
#pragma unroll
    for (int c = 0; c < 10; ++c) p[c] = 0.0f;
    for (int k = t; k < 768; k += 256) {
        float zv = z[k];
#pragma unroll
        for (int c = 0; c < 10; ++c) p[c] += zv * W4[k * 10 + c];
    }
#pragma unroll
    for (int c = 0; c < 10; ++c) atomicAdd(&red[c], p[c]);
    __syncthreads();
    if (t == 0) {
        float l[10], m = -1e30f;
#pragma unroll
        for (int c = 0; c < 10; ++c) {
            l[c] = red[c] + b4[c];
            m = fmaxf(m, l[c]);
        }
        float sum = 0.0f;
#pragma unroll
        for (int c = 0; c < 10; ++c) {
            l[c] = expf(l[c] - m);
            sum += l[c];
        }
        float inv = 1.0f / sum;
#pragma unroll
        for (int c = 0; c < 10; ++c) out[gI * 10 + c] = l[c] * inv;
    }
}

extern "C" void kernel_launch(void* const* d_in, const int* in_sizes, int n_in,
                              void* d_out, int out_size, void* d_ws, size_t ws_size,
                              hipStream_t stream) {
    const size_t REQUIRED = (size_t)(NODES + 1) * 64 * 2 * 2  // xs + h1s (with ZROW pad)
                          + (size_t)EDGES * 4                 // csr_src
                          + (size_t)(NODES + 1) * 4           // row_ptr
                          + (size_t)NODES * 4 * 2             // dinv1, dinv2
                          + (size_t)NBINS * 4                 // binCursor
                          + (size_t)NGRAPH * 64 * 4           // pooled
                          + 16;                               // flag
    if (ws_size < REQUIRED) {
        sentinel_kernel<<<20, 256, 0, stream>>>((float*)d_out, 64.0f);
        return;
    }

    const float* x = (const float*)d_in[0];
    const int* eiw = (const int*)d_in[1];
    const void* batch = d_in[2];
    const float* W1 = (const float*)d_in[3];
    const float* b1 = (const float*)d_in[4];
    const float* lng = (const float*)d_in[5];
    const float* lnb = (const float*)d_in[6];
    const float* W2 = (const float*)d_in[7];
    const float* b2 = (const float*)d_in[8];
    const float* W3 = (const float*)d_in[9];
    const float* b3 = (const float*)d_in[10];
    const float* g2 = (const float*)d_in[11];
    const float* be2 = (const float*)d_in[12];
    const float* W4 = (const float*)d_in[13];
    const float* b4 = (const float*)d_in[14];

    bf16* xs = (bf16*)d_ws;                               // (N+1)*64 bf16
    bf16* h1s = xs + (size_t)(NODES + 1) * 64;            // (N+1)*64 bf16 (12.8 MB)
    unsigned* staging = (unsigned*)h1s;                   // NBINS*BINCAP*4 = 9.61 MB alias
    int* csr_src = (int*)(h1s + (size_t)(NODES + 1) * 64);  // E
    int* row_ptr = csr_src + EDGES;                       // N+1
    float* dinv1 = (float*)(row_ptr + NODES + 1);         // N
    float* dinv2 = dinv1 + NODES;                         // N
    int* binCursor = (int*)(dinv2 + NODES);               // NBINS
    unsigned* pooled = (unsigned*)(binCursor + NBINS);    // G*64 (adjacent to binCursor)
    int* flag = (int*)(pooled + NGRAPH * 64);             // 1

    // one merged memset: binCursor=0 and pooled sentinel=0 (adjacent regions;
    // 0x00000000 < mapf(v) for every real float v)
    hipMemsetAsync(binCursor, 0, ((size_t)NBINS + (size_t)NGRAPH * 64) * 4, stream);

    // staging build (single edge-pass kernel; fixed-capacity bin slots)
    binPlace<<<NCHUNKS, 256, 0, stream>>>(eiw, flag, binCursor, staging);
    // csr_finalize also prescales x into xs (fused)
    csr_finalize<<<NBINS, 256, 0, stream>>>(staging, binCursor, row_ptr, dinv1, dinv2,
                                            csr_src, x, xs, h1s);

    // fused layers: 64 rows/block, 4-chain branchless-window gather (8 loads
    // in flight -- the measured knee) + MFMA
    gcn1_fused<<<(NODES + 63) / 64, 256, 0, stream>>>((const uint2*)xs, csr_src, row_ptr,
                                                      dinv1, dinv2, W1, b1, lng, lnb, h1s);
    gcn2_fused<<<(NODES + 63) / 64, 256, 0, stream>>>((const uint2*)h1s, csr_src, row_ptr,
                                                      dinv2, W2, b2, batch, flag, pooled);

    // head
    head_kernel<<<NGRAPH, 256, 0, stream>>>(pooled, W3, b3, g2, be2, W4, b4, (float*)d_out);
}